// Round 3
// baseline (952.974 us; speedup 1.0000x reference)
//
#include <hip/hip_runtime.h>
#include <math.h>

#define T_STEPS 24
#define BATCH   128
#define DGI     256
#define DHI     512
#define S_ITERS 3
#define LAMBDA  0.95f
#define ETA     0.5f
#define EPS_A   1e-6f
#define LN_EPS  1e-5f
#define EPS_N   1e-6f
#define HIST_MAX 23   // at most T-1 stored rank-1 terms

// ---------------------------------------------------------------------------
// Kernel 1: zproj[b][t][i] = sum_j Wg[i][j] * z[t][b][j]   (no recurrence)
// grid (BATCH, 3), 512 threads; each block does 8 timesteps for one batch row.
// ---------------------------------------------------------------------------
__global__ __launch_bounds__(512)
void zproj_k(const float* __restrict__ z_seq, const float* __restrict__ Wg,
             float* __restrict__ zp) {
    __shared__ __align__(16) float sh_z[8][DGI];
    const int b    = blockIdx.x;
    const int t0   = blockIdx.y * 8;
    const int tid  = threadIdx.x;
    const int lane = tid & 63;
    const int wave = tid >> 6;

    // wave w stages z row (t0+w): 64 lanes x float4 = 256 floats
    {
        const float4* src =
            (const float4*)(z_seq + ((size_t)(t0 + wave) * BATCH + b) * DGI);
        ((float4*)sh_z[wave])[lane] = src[lane];
    }
    __syncthreads();

    float acc[8];
    #pragma unroll
    for (int tt = 0; tt < 8; ++tt) acc[tt] = 0.f;

    const float4* wrow = (const float4*)(Wg + (size_t)tid * DGI);
    #pragma unroll 4
    for (int j4 = 0; j4 < DGI / 4; ++j4) {
        const float4 w = wrow[j4];
        #pragma unroll
        for (int tt = 0; tt < 8; ++tt) {
            const float4 z = ((const float4*)sh_z[tt])[j4];
            acc[tt] = fmaf(w.x, z.x, acc[tt]);
            acc[tt] = fmaf(w.y, z.y, acc[tt]);
            acc[tt] = fmaf(w.z, z.z, acc[tt]);
            acc[tt] = fmaf(w.w, z.w, acc[tt]);
        }
    }
    #pragma unroll
    for (int tt = 0; tt < 8; ++tt)
        zp[((size_t)b * T_STEPS + (t0 + tt)) * DHI + tid] = acc[tt];
}

// ---------------------------------------------------------------------------
// Kernel 2: the recurrence. One block per batch element, 512 threads.
// Rank-1 factorized A: A = sum_s coef[s] * hist_s hist_s^T, plus Gram matrix
// G[s][s'] = hist_s . hist_s' so that h.Ah and |Ah|^2 reduce to <=23-term
// scalar sums (no 512-wide block reduction except LayerNorm).
// ---------------------------------------------------------------------------
template<bool ZP>
__global__ __launch_bounds__(512)
void corernn_kernel(const float* __restrict__ z_seq,
                    const float* __restrict__ Wh,
                    const float* __restrict__ Wg,
                    const float* __restrict__ b_h,
                    const float* __restrict__ gamma,
                    const float* __restrict__ beta,
                    const float* __restrict__ alpha_fw,
                    const float* __restrict__ zp,
                    float* __restrict__ out) {
    __shared__ __align__(16) float sh_hist[HIST_MAX][DHI];
    __shared__ __align__(16) float sh_hs[2][DHI];      // ping-pong h buffers
    __shared__ __align__(16) float sh_G[HIST_MAX][64]; // Gram, padded cols
    __shared__ float  sh_coef[32];
    __shared__ float  sh_dot[32];
    __shared__ float2 sh_red[8];
    __shared__ __align__(16) float sh_z[DGI];          // fallback path only

    const int tid  = threadIdx.x;
    const int lane = tid & 63;
    const int wave = tid >> 6;
    const int b    = blockIdx.x;

    const float bh_r = b_h[tid];
    const float g_r  = gamma[tid];
    const float bt_r = beta[tid];

    float kpow;
    {
        const float a  = alpha_fw[0];
        const float ax = fabsf(a);
        const float sp = (ax > 20.f) ? ax : log1pf(expf(ax));
        kpow = (a >= 0.f) ? (1.f + sp) : (1.f / (1.f + sp));
    }

    // zero Gram (padded columns must be 0, not poison)
    for (int i = tid; i < HIST_MAX * 64; i += DHI) ((float*)sh_G)[i] = 0.f;
    if (!ZP) { if (tid < DGI) sh_z[tid] = z_seq[(size_t)b * DGI + tid]; }
    __syncthreads();

    int   p = 0;          // parity of the buffer holding the current h
    float hs_i = 0.f, hbase_i = 0.f;

    for (int t = 0; t < T_STEPS; ++t) {
        // ---- GEMV: h_base = b_h + Wh.h + zproj[t]  (h==0 at t==0)
        float a0 = bh_r, a1 = 0.f, a2 = 0.f, a3 = 0.f;
        if (ZP) {
            a0 += zp[((size_t)b * T_STEPS + t) * DHI + tid];
        } else {
            const float4* wrow = (const float4*)(Wg + (size_t)tid * DGI);
            const float4* z4   = (const float4*)sh_z;
            #pragma unroll 4
            for (int j4 = 0; j4 < DGI / 4; ++j4) {
                const float4 w = wrow[j4];
                const float4 h = z4[j4];
                a0 = fmaf(w.x, h.x, a0); a1 = fmaf(w.y, h.y, a1);
                a2 = fmaf(w.z, h.z, a2); a3 = fmaf(w.w, h.w, a3);
            }
        }
        if (t > 0) {
            const float4* wrow = (const float4*)(Wh + (size_t)tid * DHI);
            const float4* h4   = (const float4*)sh_hs[p];
            #pragma unroll 4
            for (int j4 = 0; j4 < DHI / 4; ++j4) {
                const float4 w = wrow[j4];
                const float4 h = h4[j4];
                a0 = fmaf(w.x, h.x, a0); a1 = fmaf(w.y, h.y, a1);
                a2 = fmaf(w.z, h.z, a2); a3 = fmaf(w.w, h.w, a3);
            }
        }
        hbase_i = (a0 + a1) + (a2 + a3);
        hs_i = fmaxf(hbase_i, 0.f);
        p ^= 1;
        sh_hs[p][tid] = hs_i;
        __syncthreads();                                  // barrier 1

        // ---- inner iterations
        for (int it = 0; it < S_ITERS; ++it) {
            const float* hcur = sh_hs[p];
            float h8[8];
            #pragma unroll
            for (int q = 0; q < 8; ++q) h8[q] = hcur[lane + 64 * q];

            // dots phase: wave-split over s in [0..t]; s==t is the self-dot
            for (int s = wave; s <= t; s += 8) {
                float d = 0.f;
                if (s == t) {
                    #pragma unroll
                    for (int q = 0; q < 8; ++q) d = fmaf(h8[q], h8[q], d);
                } else {
                    const float* vr = sh_hist[s];
                    #pragma unroll
                    for (int q = 0; q < 8; ++q) d = fmaf(vr[lane + 64 * q], h8[q], d);
                }
                #pragma unroll
                for (int off = 32; off > 0; off >>= 1) d += __shfl_xor(d, off, 64);
                if (lane == 0) sh_dot[s] = d;
            }
            __syncthreads();                              // barrier 2

            // fused scalar phase (per-thread redundant; w_s = coef[s]*dot[s]
            // read directly from LDS — both are broadcast loads, no staging)
            float dl = 0.f, w_l = 0.f;
            if (lane < t) { dl = sh_dot[lane]; w_l = sh_coef[lane] * dl; }

            float gsum = 0.f, Ah = 0.f;
            for (int s = 0; s < t; ++s) {
                const float ws = sh_coef[s] * sh_dot[s];  // uniform (broadcast)
                gsum = fmaf(ws, sh_G[s][lane], gsum);
                Ah   = fmaf(ws, sh_hist[s][tid], Ah);
            }
            float pa = w_l * dl;                          // -> h.Ah
            float pb = w_l * gsum;                        // -> |Ah|^2
            #pragma unroll
            for (int off = 32; off > 0; off >>= 1) {
                pa += __shfl_xor(pa, off, 64);
                pb += __shfl_xor(pb, off, 64);
            }
            const float n1 = fmaxf(sqrtf(sh_dot[t]), EPS_N);
            const float n2 = fmaxf(sqrtf(fmaxf(pb, 0.f)), EPS_N);
            float R = pa / (n1 * n2);
            R = fminf(fmaxf(R, 0.f), 1.f);
            const float alpha = 1.f - __powf(1.f - R, kpow);

            const float y = (1.f - alpha * alpha) * hbase_i + alpha * Ah;

            // LayerNorm reduction: one per-wave butterfly + one barrier
            float q0 = y, q1 = y * y;
            #pragma unroll
            for (int off = 32; off > 0; off >>= 1) {
                q0 += __shfl_xor(q0, off, 64);
                q1 += __shfl_xor(q1, off, 64);
            }
            if (lane == 0) sh_red[wave] = make_float2(q0, q1);
            __syncthreads();                              // barrier 3

            float s0 = 0.f, s1 = 0.f;
            #pragma unroll
            for (int w = 0; w < 8; ++w) {
                const float2 r = sh_red[w];
                s0 += r.x; s1 += r.y;
            }
            const float mean = s0 * (1.f / DHI);
            const float var  = fmaf(s1, 1.f / DHI, -mean * mean);
            const float rstd = rsqrtf(var + LN_EPS);
            hs_i = fmaxf(fmaf((y - mean) * rstd, g_r, bt_r), 0.f);
            p ^= 1;
            sh_hs[p][tid] = hs_i;
            // fallback: stage next timestep's z before the barrier
            if (!ZP && it == S_ITERS - 1 && t + 1 < T_STEPS && tid < DGI)
                sh_z[tid] = z_seq[((size_t)(t + 1) * BATCH + b) * DGI + tid];
            __syncthreads();                              // barrier 4
        }

        if (t < T_STEPS - 1) {
            // history append: Gram row + coef; overlaps with next GEMV
            // (visibility for step t+1 readers is via t+1's barrier 1)
            const float* hcur = sh_hs[p];
            float h8[8];
            #pragma unroll
            for (int q = 0; q < 8; ++q) h8[q] = hcur[lane + 64 * q];
            for (int s = wave; s <= t; s += 8) {
                float d = 0.f;
                if (s == t) {
                    #pragma unroll
                    for (int q = 0; q < 8; ++q) d = fmaf(h8[q], h8[q], d);
                } else {
                    const float* vr = sh_hist[s];
                    #pragma unroll
                    for (int q = 0; q < 8; ++q) d = fmaf(vr[lane + 64 * q], h8[q], d);
                }
                #pragma unroll
                for (int off = 32; off > 0; off >>= 1) d += __shfl_xor(d, off, 64);
                if (lane == 0) {
                    if (s == t) {
                        sh_G[t][t] = d;
                        sh_coef[t] = ETA / (d + EPS_A);
                    } else {
                        sh_G[t][s] = d;
                        sh_G[s][t] = d;
                    }
                }
            }
            if (tid < t) sh_coef[tid] *= LAMBDA;   // lambda-decay existing terms
            sh_hist[t][tid] = hs_i;
        } else {
            out[(size_t)b * DHI + tid] = hs_i;
        }
    }
}

extern "C" void kernel_launch(void* const* d_in, const int* in_sizes, int n_in,
                              void* d_out, int out_size, void* d_ws, size_t ws_size,
                              hipStream_t stream) {
    const float* z_seq    = (const float*)d_in[0];
    const float* W_h      = (const float*)d_in[1];
    const float* W_g      = (const float*)d_in[2];
    const float* b_h      = (const float*)d_in[3];
    const float* gamma    = (const float*)d_in[4];
    const float* beta     = (const float*)d_in[5];
    const float* alpha_fw = (const float*)d_in[6];
    float* out = (float*)d_out;

    const size_t zp_bytes = (size_t)BATCH * T_STEPS * DHI * sizeof(float);
    if (ws_size >= zp_bytes) {
        float* zp = (float*)d_ws;
        zproj_k<<<dim3(BATCH, T_STEPS / 8), 512, 0, stream>>>(z_seq, W_g, zp);
        corernn_kernel<true><<<BATCH, DHI, 0, stream>>>(z_seq, W_h, W_g, b_h, gamma,
                                                        beta, alpha_fw, zp, out);
    } else {
        corernn_kernel<false><<<BATCH, DHI, 0, stream>>>(z_seq, W_h, W_g, b_h, gamma,
                                                         beta, alpha_fw, nullptr, out);
    }
}

// Round 4
// 483.377 us; speedup vs baseline: 1.9715x; 1.9715x over previous
//
#include <hip/hip_runtime.h>
#include <math.h>

#define T_STEPS 24
#define BATCH   128
#define DGI     256
#define DHI     512
#define S_ITERS 3
#define LAMBDA  0.95f
#define ETA     0.5f
#define EPS_A   1e-6f
#define LN_EPS  1e-5f
#define EPS_N   1e-6f
#define HIST_MAX 23   // at most T-1 stored rank-1 terms

// ---------------------------------------------------------------------------
// Tiled transpose: dst[c*R + r] = src[r*C + c].  R,C multiples of 32.
// ---------------------------------------------------------------------------
__global__ void transpose_k(const float* __restrict__ src, float* __restrict__ dst,
                            int R, int C) {
    __shared__ float tile[32][33];
    const int tx = threadIdx.x & 31;
    const int ty = threadIdx.x >> 5;          // 0..7 (256 threads)
    const int c0 = blockIdx.x * 32;
    const int r0 = blockIdx.y * 32;
    #pragma unroll
    for (int i = 0; i < 32; i += 8)
        tile[ty + i][tx] = src[(size_t)(r0 + ty + i) * C + (c0 + tx)];
    __syncthreads();
    #pragma unroll
    for (int i = 0; i < 32; i += 8)
        dst[(size_t)(c0 + ty + i) * R + (r0 + tx)] = tile[tx][ty + i];
}

// ---------------------------------------------------------------------------
// zproj[b][t][i] = sum_j Wg[i][j] * z[t][b][j]   (no recurrence; parallel)
// grid (BATCH, 3), 512 threads; each block does 8 timesteps of one batch row.
// ---------------------------------------------------------------------------
__global__ __launch_bounds__(512)
void zproj_k(const float* __restrict__ z_seq, const float* __restrict__ Wg,
             float* __restrict__ zp) {
    __shared__ __align__(16) float sh_z[8][DGI];
    const int b    = blockIdx.x;
    const int t0   = blockIdx.y * 8;
    const int tid  = threadIdx.x;
    const int lane = tid & 63;
    const int wave = tid >> 6;
    {
        const float4* src =
            (const float4*)(z_seq + ((size_t)(t0 + wave) * BATCH + b) * DGI);
        ((float4*)sh_z[wave])[lane] = src[lane];
    }
    __syncthreads();

    float acc[8];
    #pragma unroll
    for (int tt = 0; tt < 8; ++tt) acc[tt] = 0.f;

    const float4* wrow = (const float4*)(Wg + (size_t)tid * DGI);
    #pragma unroll 4
    for (int j4 = 0; j4 < DGI / 4; ++j4) {
        const float4 w = wrow[j4];
        #pragma unroll
        for (int tt = 0; tt < 8; ++tt) {
            const float4 z = ((const float4*)sh_z[tt])[j4];
            acc[tt] = fmaf(w.x, z.x, acc[tt]);
            acc[tt] = fmaf(w.y, z.y, acc[tt]);
            acc[tt] = fmaf(w.z, z.z, acc[tt]);
            acc[tt] = fmaf(w.w, z.w, acc[tt]);
        }
    }
    #pragma unroll
    for (int tt = 0; tt < 8; ++tt)
        zp[((size_t)b * T_STEPS + (t0 + tt)) * DHI + tid] = acc[tt];
}

// ---------------------------------------------------------------------------
// Recurrence. One block per batch element, 512 threads.
// ZP=true: Wh is TRANSPOSED (WhT[j][i]) and zp holds precomputed Wg.z.
//   GEMV remap: thread=(i4=tid&127, jg=tid>>7) accumulates outputs 4*i4..+3
//   over j in [jg*128, jg*128+128) -> coalesced float4 loads, 128/thread.
// A is rank-1 factorized with an incrementally-maintained Gram matrix.
// ---------------------------------------------------------------------------
template<bool ZP>
__global__ __launch_bounds__(512)
void corernn_kernel(const float* __restrict__ z_seq,
                    const float* __restrict__ Wh,   // ZP ? WhT[j][i] : Wh[i][j]
                    const float* __restrict__ Wg,
                    const float* __restrict__ b_h,
                    const float* __restrict__ gamma,
                    const float* __restrict__ beta,
                    const float* __restrict__ alpha_fw,
                    const float* __restrict__ zp,
                    float* __restrict__ out) {
    __shared__ __align__(16) float  sh_hist[HIST_MAX][DHI];
    __shared__ __align__(16) float  sh_hs[2][DHI];      // ping-pong h buffers
    __shared__ __align__(16) float  sh_G[HIST_MAX][64]; // Gram, padded cols
    __shared__ __align__(16) float4 sh_part[4][128];    // GEMV jg-partials (8KB)
    __shared__ float  sh_coef[32];
    __shared__ float  sh_dot[32];
    __shared__ float2 sh_red[8];
    __shared__ __align__(16) float sh_z[DGI];           // fallback path only

    const int tid  = threadIdx.x;
    const int lane = tid & 63;
    const int wave = tid >> 6;
    const int b    = blockIdx.x;

    const float bh_r = b_h[tid];
    const float g_r  = gamma[tid];
    const float bt_r = beta[tid];

    float kpow;
    {
        const float a  = alpha_fw[0];
        const float ax = fabsf(a);
        const float sp = (ax > 20.f) ? ax : log1pf(expf(ax));
        kpow = (a >= 0.f) ? (1.f + sp) : (1.f / (1.f + sp));
    }

    // zero Gram (padded columns must be 0, not poison)
    for (int i = tid; i < HIST_MAX * 64; i += DHI) ((float*)sh_G)[i] = 0.f;
    if (!ZP) { if (tid < DGI) sh_z[tid] = z_seq[(size_t)b * DGI + tid]; }
    __syncthreads();

    int   p = 0;          // parity of the buffer holding the current h
    float hs_i = 0.f, hbase_i = 0.f;

    for (int t = 0; t < T_STEPS; ++t) {
        // ---- GEMV: h_base = b_h + Wh.h + Wg.z   (h==0 at t==0)
        if (ZP) {
            const float zval = zp[((size_t)b * T_STEPS + t) * DHI + tid];
            if (t > 0) {
                const int i4 = tid & 127;
                const int jg = tid >> 7;
                const int jbase = jg * 128;
                const float4* __restrict__ w4 = (const float4*)Wh;
                const size_t wrow = (size_t)jbase * (DHI / 4) + i4;
                const float4* h4p = (const float4*)(sh_hs[p] + jbase);
                float4 acc = make_float4(0.f, 0.f, 0.f, 0.f);
                #pragma unroll 4
                for (int j4 = 0; j4 < 32; ++j4) {
                    const float4 h4 = h4p[j4];
                    const float4 wa = w4[wrow + (size_t)(4 * j4 + 0) * 128];
                    const float4 wb = w4[wrow + (size_t)(4 * j4 + 1) * 128];
                    const float4 wc = w4[wrow + (size_t)(4 * j4 + 2) * 128];
                    const float4 wd = w4[wrow + (size_t)(4 * j4 + 3) * 128];
                    acc.x = fmaf(wa.x, h4.x, fmaf(wb.x, h4.y, fmaf(wc.x, h4.z, fmaf(wd.x, h4.w, acc.x))));
                    acc.y = fmaf(wa.y, h4.x, fmaf(wb.y, h4.y, fmaf(wc.y, h4.z, fmaf(wd.y, h4.w, acc.y))));
                    acc.z = fmaf(wa.z, h4.x, fmaf(wb.z, h4.y, fmaf(wc.z, h4.z, fmaf(wd.z, h4.w, acc.z))));
                    acc.w = fmaf(wa.w, h4.x, fmaf(wb.w, h4.y, fmaf(wc.w, h4.z, fmaf(wd.w, h4.w, acc.w))));
                }
                sh_part[jg][i4] = acc;
                __syncthreads();                          // barrier A
                const float* pp = (const float*)sh_part;  // [jg*512 + i]
                hbase_i = bh_r + zval +
                          ((pp[tid] + pp[512 + tid]) + (pp[1024 + tid] + pp[1536 + tid]));
            } else {
                hbase_i = bh_r + zval;
            }
        } else {
            float a0 = bh_r, a1 = 0.f, a2 = 0.f, a3 = 0.f;
            {
                const float4* wrow = (const float4*)(Wg + (size_t)tid * DGI);
                const float4* z4   = (const float4*)sh_z;
                #pragma unroll 4
                for (int j4 = 0; j4 < DGI / 4; ++j4) {
                    const float4 w = wrow[j4];
                    const float4 h = z4[j4];
                    a0 = fmaf(w.x, h.x, a0); a1 = fmaf(w.y, h.y, a1);
                    a2 = fmaf(w.z, h.z, a2); a3 = fmaf(w.w, h.w, a3);
                }
            }
            if (t > 0) {
                const float4* wrow = (const float4*)(Wh + (size_t)tid * DHI);
                const float4* h4   = (const float4*)sh_hs[p];
                #pragma unroll 4
                for (int j4 = 0; j4 < DHI / 4; ++j4) {
                    const float4 w = wrow[j4];
                    const float4 h = h4[j4];
                    a0 = fmaf(w.x, h.x, a0); a1 = fmaf(w.y, h.y, a1);
                    a2 = fmaf(w.z, h.z, a2); a3 = fmaf(w.w, h.w, a3);
                }
            }
            hbase_i = (a0 + a1) + (a2 + a3);
        }
        hs_i = fmaxf(hbase_i, 0.f);
        p ^= 1;
        sh_hs[p][tid] = hs_i;
        __syncthreads();                                  // barrier 1

        // ---- inner iterations (t==0: A==0 -> y==h_base every iter -> 1 pass)
        const int niter = (t == 0) ? 1 : S_ITERS;
        for (int it = 0; it < niter; ++it) {
            const float* hcur = sh_hs[p];
            float h8[8];
            #pragma unroll
            for (int q = 0; q < 8; ++q) h8[q] = hcur[lane + 64 * q];

            // dots phase: wave-split over s in [0..t]; s==t is the self-dot
            for (int s = wave; s <= t; s += 8) {
                float d = 0.f;
                if (s == t) {
                    #pragma unroll
                    for (int q = 0; q < 8; ++q) d = fmaf(h8[q], h8[q], d);
                } else {
                    const float* vr = sh_hist[s];
                    #pragma unroll
                    for (int q = 0; q < 8; ++q) d = fmaf(vr[lane + 64 * q], h8[q], d);
                }
                #pragma unroll
                for (int off = 32; off > 0; off >>= 1) d += __shfl_xor(d, off, 64);
                if (lane == 0) sh_dot[s] = d;
            }
            __syncthreads();                              // barrier 2

            // scalar phase (per-thread redundant; broadcast LDS reads only)
            float dl = 0.f, w_l = 0.f;
            if (lane < t) { dl = sh_dot[lane]; w_l = sh_coef[lane] * dl; }

            float gsum = 0.f, Ah = 0.f;
            for (int s = 0; s < t; ++s) {
                const float ws = sh_coef[s] * sh_dot[s];  // uniform (broadcast)
                gsum = fmaf(ws, sh_G[s][lane], gsum);
                Ah   = fmaf(ws, sh_hist[s][tid], Ah);
            }
            float pa = w_l * dl;                          // -> h.Ah
            float pb = w_l * gsum;                        // -> |Ah|^2
            #pragma unroll
            for (int off = 32; off > 0; off >>= 1) {
                pa += __shfl_xor(pa, off, 64);
                pb += __shfl_xor(pb, off, 64);
            }
            const float n1 = fmaxf(sqrtf(sh_dot[t]), EPS_N);
            const float n2 = fmaxf(sqrtf(fmaxf(pb, 0.f)), EPS_N);
            float R = pa / (n1 * n2);
            R = fminf(fmaxf(R, 0.f), 1.f);
            const float alpha = 1.f - __powf(1.f - R, kpow);

            const float y = (1.f - alpha * alpha) * hbase_i + alpha * Ah;

            // LayerNorm reduction: one per-wave butterfly + one barrier
            float q0 = y, q1 = y * y;
            #pragma unroll
            for (int off = 32; off > 0; off >>= 1) {
                q0 += __shfl_xor(q0, off, 64);
                q1 += __shfl_xor(q1, off, 64);
            }
            if (lane == 0) sh_red[wave] = make_float2(q0, q1);
            __syncthreads();                              // barrier 3

            float s0 = 0.f, s1 = 0.f;
            #pragma unroll
            for (int w = 0; w < 8; ++w) {
                const float2 r = sh_red[w];
                s0 += r.x; s1 += r.y;
            }
            const float mean = s0 * (1.f / DHI);
            const float var  = fmaf(s1, 1.f / DHI, -mean * mean);
            const float rstd = rsqrtf(var + LN_EPS);
            hs_i = fmaxf(fmaf((y - mean) * rstd, g_r, bt_r), 0.f);
            p ^= 1;
            sh_hs[p][tid] = hs_i;
            // fallback path: stage next timestep's z before the barrier
            if (!ZP && it == niter - 1 && t + 1 < T_STEPS && tid < DGI)
                sh_z[tid] = z_seq[((size_t)(t + 1) * BATCH + b) * DGI + tid];
            __syncthreads();                              // barrier 4
        }

        if (t < T_STEPS - 1) {
            // history append: Gram row + coef; overlaps with next GEMV
            // (visibility for step t+1 readers via t+1's barriers A/1)
            const float* hcur = sh_hs[p];
            float h8[8];
            #pragma unroll
            for (int q = 0; q < 8; ++q) h8[q] = hcur[lane + 64 * q];
            for (int s = wave; s <= t; s += 8) {
                float d = 0.f;
                if (s == t) {
                    #pragma unroll
                    for (int q = 0; q < 8; ++q) d = fmaf(h8[q], h8[q], d);
                } else {
                    const float* vr = sh_hist[s];
                    #pragma unroll
                    for (int q = 0; q < 8; ++q) d = fmaf(vr[lane + 64 * q], h8[q], d);
                }
                #pragma unroll
                for (int off = 32; off > 0; off >>= 1) d += __shfl_xor(d, off, 64);
                if (lane == 0) {
                    if (s == t) {
                        sh_G[t][t] = d;
                        sh_coef[t] = ETA / (d + EPS_A);
                    } else {
                        sh_G[t][s] = d;
                        sh_G[s][t] = d;
                    }
                }
            }
            if (tid < t) sh_coef[tid] *= LAMBDA;   // lambda-decay existing terms
            sh_hist[t][tid] = hs_i;
        } else {
            out[(size_t)b * DHI + tid] = hs_i;
        }
    }
}

extern "C" void kernel_launch(void* const* d_in, const int* in_sizes, int n_in,
                              void* d_out, int out_size, void* d_ws, size_t ws_size,
                              hipStream_t stream) {
    const float* z_seq    = (const float*)d_in[0];
    const float* W_h      = (const float*)d_in[1];
    const float* W_g      = (const float*)d_in[2];
    const float* b_h      = (const float*)d_in[3];
    const float* gamma    = (const float*)d_in[4];
    const float* beta     = (const float*)d_in[5];
    const float* alpha_fw = (const float*)d_in[6];
    float* out = (float*)d_out;

    const size_t zp_elems  = (size_t)BATCH * T_STEPS * DHI;          // 6 MB
    const size_t wht_elems = (size_t)DHI * DHI;                      // 1 MB
    const size_t needed = (zp_elems + wht_elems) * sizeof(float);
    if (ws_size >= needed) {
        float* zp  = (float*)d_ws;
        float* WhT = zp + zp_elems;
        transpose_k<<<dim3(DHI / 32, DHI / 32), 256, 0, stream>>>(W_h, WhT, DHI, DHI);
        zproj_k<<<dim3(BATCH, T_STEPS / 8), 512, 0, stream>>>(z_seq, W_g, zp);
        corernn_kernel<true><<<BATCH, DHI, 0, stream>>>(z_seq, WhT, W_g, b_h, gamma,
                                                        beta, alpha_fw, zp, out);
    } else {
        corernn_kernel<false><<<BATCH, DHI, 0, stream>>>(z_seq, W_h, W_g, b_h, gamma,
                                                         beta, alpha_fw, nullptr, out);
    }
}